// Round 1
// baseline (2453.417 us; speedup 1.0000x reference)
//
#include <hip/hip_runtime.h>

#define H 32
#define FIN 64

// ---------------- CSR build ----------------

__global__ void k_hist(const int* __restrict__ dst, int* __restrict__ deg, int E) {
    int e = blockIdx.x * blockDim.x + threadIdx.x;
    if (e < E) atomicAdd(&deg[dst[e]], 1);
}

// single-block exclusive scan (wave-scan + wave-sum scan), n up to ~1e5
__global__ void k_scan(const int* __restrict__ deg, int* __restrict__ offs, int n) {
    __shared__ int wsum[16];
    __shared__ int wbase[16];
    __shared__ int carry_s;
    int tid = threadIdx.x;
    int lane = tid & 63, wid = tid >> 6;
    if (tid == 0) carry_s = 0;
    __syncthreads();
    int nb = blockDim.x; // 1024
    for (int base = 0; base < n; base += nb) {
        int i = base + tid;
        int v = (i < n) ? deg[i] : 0;
        int incl = v;
        #pragma unroll
        for (int d = 1; d < 64; d <<= 1) {
            int t = __shfl_up(incl, d, 64);
            if (lane >= d) incl += t;
        }
        if (lane == 63) wsum[wid] = incl;
        __syncthreads();
        if (tid == 0) {
            int acc = 0;
            #pragma unroll
            for (int w = 0; w < 16; ++w) { wbase[w] = acc; acc += wsum[w]; }
            wsum[0] = acc; // block total
        }
        __syncthreads();
        if (i < n) offs[i] = carry_s + wbase[wid] + incl - v;
        __syncthreads();
        if (tid == 0) carry_s += wsum[0];
        __syncthreads();
    }
    if (tid == 0) offs[n] = carry_s;
}

__global__ void k_dinv(const int* __restrict__ offs, float* __restrict__ dinv, int n) {
    int i = blockIdx.x * blockDim.x + threadIdx.x;
    if (i < n) dinv[i] = rsqrtf((float)(offs[i + 1] - offs[i] + 1));
}

__global__ void k_fill(const int* __restrict__ src, const int* __restrict__ dst,
                       const int* __restrict__ offs, int* __restrict__ cursor,
                       int* __restrict__ csr, int E) {
    int e = blockIdx.x * blockDim.x + threadIdx.x;
    if (e < E) {
        int d = dst[e];
        int p = atomicAdd(&cursor[d], 1);
        csr[offs[d] + p] = src[e];
    }
}

// ---------------- dense node transforms ----------------

// xw = x @ W_gcn   (x: [n,64], W: [64,32])
__global__ void k_gemm64(const float* __restrict__ x, const float* __restrict__ W,
                         float* __restrict__ xw, int n) {
    __shared__ float Ws[FIN * H];
    __shared__ float xs[8 * FIN];
    int tid = threadIdx.x;
    for (int i = tid; i < FIN * H; i += 256) Ws[i] = W[i];
    int nodeBase = blockIdx.x * 8;
    for (int i = tid; i < 8 * FIN; i += 256) {
        int node = nodeBase + i / FIN;
        xs[i] = (node < n) ? x[(size_t)node * FIN + (i & 63)] : 0.f;
    }
    __syncthreads();
    int nl = tid >> 5, f = tid & 31;
    int node = nodeBase + nl;
    if (node < n) {
        float acc = 0.f;
        #pragma unroll
        for (int ff = 0; ff < FIN; ++ff) acc += xs[nl * FIN + ff] * Ws[ff * H + f];
        xw[(size_t)node * H + f] = acc;
    }
}

// GCN aggregate: h = relu( (sum_{s->g} xw[s]*dinv[s])*dinv[g] + xw[g]*dinv[g]^2 + b )
__global__ void k_gcn(const float* __restrict__ xw, const int* __restrict__ offs,
                      const int* __restrict__ csr, const float* __restrict__ dinv,
                      const float* __restrict__ b, float* __restrict__ h, int n) {
    int g = (blockIdx.x * blockDim.x + threadIdx.x) >> 5;
    int f = threadIdx.x & 31;
    if (g >= n) return;
    int s0 = offs[g], s1 = offs[g + 1];
    float acc = 0.f;
    for (int p = s0; p < s1; ++p) {
        int s = csr[p];
        acc += xw[(size_t)s * H + f] * dinv[s];
    }
    float di = dinv[g];
    float out = acc * di + xw[(size_t)g * H + f] * di * di + b[f];
    h[(size_t)g * H + f] = fmaxf(out, 0.f);
}

// SAGE: hout = relu( mean_{s->g}(hin[s]) @ Wl + bl + hin[g] @ Wr )
__global__ void k_sage(const float* __restrict__ hin, const int* __restrict__ offs,
                       const int* __restrict__ csr, const float* __restrict__ Wl,
                       const float* __restrict__ bl, const float* __restrict__ Wr,
                       float* __restrict__ hout, int n) {
    __shared__ float Wls[H * H], Wrs[H * H];
    int tid = threadIdx.x;
    for (int i = tid; i < H * H; i += 256) { Wls[i] = Wl[i]; Wrs[i] = Wr[i]; }
    __syncthreads();
    int g = (blockIdx.x * blockDim.x + tid) >> 5;
    int f = tid & 31;
    if (g >= n) return;
    int s0 = offs[g], s1 = offs[g + 1];
    float acc = 0.f;
    for (int p = s0; p < s1; ++p) {
        int s = csr[p];
        acc += hin[(size_t)s * H + f];
    }
    float cnt = (float)(s1 - s0);
    float mean = acc / fmaxf(cnt, 1.f);
    float hf = hin[(size_t)g * H + f];
    float o = bl[f];
    #pragma unroll
    for (int ff = 0; ff < H; ++ff) {
        float mv = __shfl(mean, ff, 32);
        float hv = __shfl(hf, ff, 32);
        o += mv * Wls[ff * H + f] + hv * Wrs[ff * H + f];
    }
    hout[(size_t)g * H + f] = fmaxf(o, 0.f);
}

// ---------------- attention pooling ----------------

__global__ void k_poolsum(const float* __restrict__ rep, const int* __restrict__ batch,
                          float* __restrict__ sums, float* __restrict__ cntg, int n) {
    int g = (blockIdx.x * blockDim.x + threadIdx.x) >> 5;
    int f = threadIdx.x & 31;
    if (g >= n) return;
    int b = batch[g];
    atomicAdd(&sums[b * H + f], rep[(size_t)g * H + f]);
    if (f == 0) atomicAdd(&cntg[b], 1.f);
}

__global__ void k_ctx(const float* __restrict__ sums, const float* __restrict__ cntg,
                      const float* __restrict__ wc, float* __restrict__ ctx, int Bn) {
    int idx = blockIdx.x * blockDim.x + threadIdx.x;
    if (idx >= Bn * H) return;
    int b = idx >> 5, f = idx & 31;
    float inv = 1.f / fmaxf(cntg[b], 1.f);
    float acc = 0.f;
    #pragma unroll
    for (int ff = 0; ff < H; ++ff) acc += sums[b * H + ff] * inv * wc[ff * H + f];
    ctx[idx] = tanhf(acc);
}

__global__ void k_gatepool(const float* __restrict__ rep, const int* __restrict__ batch,
                           const float* __restrict__ ctx, float* __restrict__ pooled, int n) {
    int g = (blockIdx.x * blockDim.x + threadIdx.x) >> 5;
    int f = threadIdx.x & 31;
    if (g >= n) return;
    int b = batch[g];
    float r = rep[(size_t)g * H + f];
    float d = r * ctx[b * H + f];
    #pragma unroll
    for (int m = 16; m >= 1; m >>= 1) d += __shfl_xor(d, m, 32);
    float gate = 1.f / (1.f + expf(-d));
    atomicAdd(&pooled[b * H + f], gate * r);
}

// ---------------- NTN + final MLP ----------------

__global__ void k_ntn(const float* __restrict__ hi, const float* __restrict__ hj,
                      const float* __restrict__ Wntn, const float* __restrict__ Vntn,
                      const float* __restrict__ bntn, const float* __restrict__ mlpw,
                      const float* __restrict__ mlpb, float* __restrict__ out, int Bn) {
    __shared__ float his[8 * H], hjs[8 * H];
    int tid = threadIdx.x;
    int bb = blockIdx.x * 8;
    for (int i = tid; i < 8 * H; i += 256) {
        int b = bb + i / H;
        his[i] = (b < Bn) ? hi[b * H + (i & 31)] : 0.f;
        hjs[i] = (b < Bn) ? hj[b * H + (i & 31)] : 0.f;
    }
    __syncthreads();
    int bl = tid >> 5, k = tid & 31;
    int b = bb + bl;
    if (b >= Bn) return;
    const float* W = Wntn + k * H * H;
    float g = bntn[k];
    #pragma unroll 4
    for (int i = 0; i < H; ++i) {
        float acc = 0.f;
        #pragma unroll
        for (int j = 0; j < H; ++j) acc += W[i * H + j] * hjs[bl * H + j];
        g += his[bl * H + i] * acc;
    }
    const float* V = Vntn + k * 2 * H;
    #pragma unroll
    for (int f = 0; f < H; ++f) g += his[bl * H + f] * V[f] + hjs[bl * H + f] * V[H + f];
    float sc = g * mlpw[k];
    #pragma unroll
    for (int m = 16; m >= 1; m >>= 1) sc += __shfl_xor(sc, m, 32);
    if (k == 0) out[b] = sc + mlpb[0];
}

// ---------------- host orchestration ----------------

extern "C" void kernel_launch(void* const* d_in, const int* in_sizes, int n_in,
                              void* d_out, int out_size, void* d_ws, size_t ws_size,
                              hipStream_t stream) {
    const float* x_i      = (const float*)d_in[0];
    const int*   ei_i     = (const int*)d_in[1];
    const int*   batch_i  = (const int*)d_in[2];
    const float* x_j      = (const float*)d_in[3];
    const int*   ei_j     = (const int*)d_in[4];
    const int*   batch_j  = (const int*)d_in[5];
    const float* W_gcn    = (const float*)d_in[6];
    const float* b_gcn    = (const float*)d_in[7];
    const float* sage_l   = (const float*)d_in[8];
    const float* sage_bl  = (const float*)d_in[9];
    const float* sage_r   = (const float*)d_in[10];
    const float* weight_c = (const float*)d_in[11];
    const float* W_ntn    = (const float*)d_in[12];
    const float* V_ntn    = (const float*)d_in[13];
    const float* b_ntn    = (const float*)d_in[14];
    const float* mlp_w    = (const float*)d_in[15];
    const float* mlp_b    = (const float*)d_in[16];

    const int N = in_sizes[0] / FIN;
    const int E = in_sizes[1] / 2;
    const int B = out_size;

    char* p = (char*)d_ws;
    auto alloc = [&](size_t bytes) {
        char* r = p;
        p += (bytes + 255) & ~(size_t)255;
        return r;
    };
    int*   offs     = (int*)alloc((size_t)(N + 1) * 4);
    int*   work     = (int*)alloc((size_t)N * 4);       // deg, then cursor
    int*   csr      = (int*)alloc((size_t)E * 4);
    float* dinv     = (float*)alloc((size_t)N * 4);
    float* h0       = (float*)alloc((size_t)N * H * 4);
    float* h1       = (float*)alloc((size_t)N * H * 4);
    float* sums     = (float*)alloc((size_t)B * H * 4);
    float* cntg     = (float*)alloc((size_t)B * 4);
    float* ctx      = (float*)alloc((size_t)B * H * 4);
    float* pooled_i = (float*)alloc((size_t)B * H * 4);
    float* pooled_j = (float*)alloc((size_t)B * H * 4);

    const int nodeBlocks = (N * 32 + 255) / 256;

    for (int gi = 0; gi < 2; ++gi) {
        const float* x     = gi ? x_j : x_i;
        const int*   ei    = gi ? ei_j : ei_i;
        const int*   batch = gi ? batch_j : batch_i;
        float* pooled      = gi ? pooled_j : pooled_i;
        const int* src = ei;
        const int* dst = ei + E;

        hipMemsetAsync(work, 0, (size_t)N * 4, stream);
        k_hist<<<(E + 255) / 256, 256, 0, stream>>>(dst, work, E);
        k_scan<<<1, 1024, 0, stream>>>(work, offs, N);
        k_dinv<<<(N + 255) / 256, 256, 0, stream>>>(offs, dinv, N);
        hipMemsetAsync(work, 0, (size_t)N * 4, stream);
        k_fill<<<(E + 255) / 256, 256, 0, stream>>>(src, dst, offs, work, csr, E);

        k_gemm64<<<(N + 7) / 8, 256, 0, stream>>>(x, W_gcn, h0, N);
        k_gcn<<<nodeBlocks, 256, 0, stream>>>(h0, offs, csr, dinv, b_gcn, h1, N);
        k_sage<<<nodeBlocks, 256, 0, stream>>>(h1, offs, csr, sage_l, sage_bl, sage_r, h0, N);
        k_sage<<<nodeBlocks, 256, 0, stream>>>(h0, offs, csr, sage_l + H * H, sage_bl + H,
                                               sage_r + H * H, h1, N);

        hipMemsetAsync(sums, 0, (size_t)B * H * 4, stream);
        hipMemsetAsync(cntg, 0, (size_t)B * 4, stream);
        hipMemsetAsync(pooled, 0, (size_t)B * H * 4, stream);
        k_poolsum<<<nodeBlocks, 256, 0, stream>>>(h1, batch, sums, cntg, N);
        k_ctx<<<(B * H + 255) / 256, 256, 0, stream>>>(sums, cntg, weight_c, ctx, B);
        k_gatepool<<<nodeBlocks, 256, 0, stream>>>(h1, batch, ctx, pooled, N);
    }

    k_ntn<<<(B + 7) / 8, 256, 0, stream>>>(pooled_i, pooled_j, W_ntn, V_ntn, b_ntn,
                                           mlp_w, mlp_b, (float*)d_out, B);
}